// Round 7
// baseline (238.735 us; speedup 1.0000x reference)
//
#include <hip/hip_runtime.h>
#include <hip/hip_bf16.h>

#define S_DIM 2048
#define D_DIM 512
#define B_DIM 8
#define SCALE 0.02209708691207961f  // 1/sqrt(2048)

typedef __hip_bfloat16 bf16;
typedef short bf16x8 __attribute__((ext_vector_type(8)));
typedef float f32x4 __attribute__((ext_vector_type(4)));

__device__ __forceinline__ unsigned short f2b(float f) {
  __hip_bfloat16 h = __float2bfloat16(f);
  return __builtin_bit_cast(unsigned short, h);
}
__device__ __forceinline__ float b2f(unsigned short s) {
  return __bfloat162float(__builtin_bit_cast(__hip_bfloat16, s));
}

__device__ __forceinline__ void load_lds16(const void* g, void* l) {
  __builtin_amdgcn_global_load_lds((const __attribute__((address_space(1))) void*)g,
                                   (__attribute__((address_space(3))) void*)l, 16, 0, 0);
}

// ---------------- kernel matrix f32 -> bf16 ----------------
__global__ void convert_k(const float* __restrict__ in, bf16* __restrict__ out, int n8) {
  int i = blockIdx.x * blockDim.x + threadIdx.x;
  if (i >= n8) return;
  const float4* p = (const float4*)in;
  float4 a = p[2 * i], b = p[2 * i + 1];
  bf16x8 r;
  r[0] = f2b(a.x); r[1] = f2b(a.y); r[2] = f2b(a.z); r[3] = f2b(a.w);
  r[4] = f2b(b.x); r[5] = f2b(b.y); r[6] = f2b(b.z); r[7] = f2b(b.w);
  ((bf16x8*)out)[i] = r;
}

// ---------------- transpose (B,S,D) f32 -> (B,D,S) bf16 ----------------
__global__ void transpose_f2b(const float* __restrict__ in, bf16* __restrict__ out) {
  __shared__ float tile[32][33];
  int b = blockIdx.z;
  int c0 = blockIdx.x * 32;
  int r0 = blockIdx.y * 32;
  const float* ib = in + (size_t)b * S_DIM * D_DIM;
  bf16* ob = out + (size_t)b * S_DIM * D_DIM;
  int lr = threadIdx.x >> 5, lc = threadIdx.x & 31;
#pragma unroll
  for (int i = 0; i < 4; i++)
    tile[lr + i * 8][lc] = ib[(size_t)(r0 + lr + i * 8) * D_DIM + c0 + lc];
  __syncthreads();
#pragma unroll
  for (int i = 0; i < 4; i++) {
    int cc = lr + i * 8;
    ob[(size_t)(c0 + cc) * S_DIM + r0 + lc] = __float2bfloat16(tile[lc][cc]);
  }
}

// ---------------- transpose (B,S,D) bf16 -> (B,D,S) bf16 ----------------
__global__ void transpose_b2b(const bf16* __restrict__ in, bf16* __restrict__ out) {
  __shared__ bf16 tile[32][33];
  int b = blockIdx.z;
  int c0 = blockIdx.x * 32;
  int r0 = blockIdx.y * 32;
  const bf16* ib = in + (size_t)b * S_DIM * D_DIM;
  bf16* ob = out + (size_t)b * S_DIM * D_DIM;
  int lr = threadIdx.x >> 5, lc = threadIdx.x & 31;
#pragma unroll
  for (int i = 0; i < 4; i++)
    tile[lr + i * 8][lc] = ib[(size_t)(r0 + lr + i * 8) * D_DIM + c0 + lc];
  __syncthreads();
#pragma unroll
  for (int i = 0; i < 4; i++) {
    int cc = lr + i * 8;
    ob[(size_t)(c0 + cc) * S_DIM + r0 + lc] = tile[lc][cc];
  }
}

// ---------------- h-GEMM, 8-phase v2: H[item][s][d] = sum_t A[s][t]*X[item][d][t] ------
// 256x256, BK=64, 8 waves (2m x 4n, per-wave 128x64). LDS 128KB: A 2buf x 2half x 16KB @0,
// B same @64KB. Per K-tile 4 phases {ds_reads, stage 1 half, barrier, 16-MFMA quadrant,
// barrier}; quadrants (0,0)(1,0)(1,1)(0,1); stages P1:B0(t+1) P2:B1(t+1) P3:A0(t+2)
// P4:A1(t+2)+vmcnt(4). NO lgkmcnt(0)/sched_barrier in-phase (m141/R5 lesson): compiler's
// own fine-grained lgkmcnt interleave feeds the MFMAs. All stage/read hazards are covered
// by the P4 vmcnt + >=6 intervening barriers (R5-verified), so barriers shape schedule only.
// Swizzle (R6-verified, 0 conflicts): LDS[row][slot16B] = G[row][slot ^ (row&7)].
__global__ __launch_bounds__(512, 1) void gemm_h(
    const bf16* __restrict__ A, const bf16* __restrict__ X, bf16* __restrict__ H) {
  extern __shared__ char smem[];
  const int pid = blockIdx.x;
  const int mt = pid & 7;          // XCD-pinned A panel
  const int r_ = pid >> 3;
  const int ntile = r_ & 1;
  const int item = r_ >> 1;        // 0..15
  const int m0 = mt * 256, n0 = ntile * 256;
  const bf16* Asrc = A + (size_t)m0 * S_DIM;
  const bf16* Bsrc = X + (size_t)item * (D_DIM * S_DIM) + (size_t)n0 * S_DIM;
  bf16* Hi = H + (size_t)item * (S_DIM * D_DIM);

  const int tid = threadIdx.x;
  const int w = tid >> 6, L = tid & 63;
  const int l15 = L & 15, lhi = L >> 4;
  const int wr = w >> 2, wn = w & 3;

  // staging sources (pre-swizzled)
  const int srow = w * 16 + (L >> 3);
  const int sslot = ((L & 7) ^ ((L >> 3) & 7)) * 8;
  const bf16* pA[2][2];
  const bf16* pB[2][2];
#pragma unroll
  for (int h = 0; h < 2; h++)
#pragma unroll
    for (int ld = 0; ld < 2; ld++) {
      pA[h][ld] = Asrc + (size_t)(h * 128 + srow + ld * 8) * S_DIM + sslot;
      pB[h][ld] = Bsrc + (size_t)(h * 128 + srow + ld * 8) * S_DIM + sslot;
    }

  auto stageA = [&](int t2, int half) {
    char* d = smem + (((t2 & 1) * 2 + half) << 14) + w * 2048;
    const int ko = t2 * 64;
#pragma unroll
    for (int ld = 0; ld < 2; ld++) load_lds16(pA[half][ld] + ko, d + ld * 1024);
  };
  auto stageB = [&](int t2, int half) {
    char* d = smem + 65536 + (((t2 & 1) * 2 + half) << 14) + w * 2048;
    const int ko = t2 * 64;
#pragma unroll
    for (int ld = 0; ld < 2; ld++) load_lds16(pB[half][ld] + ko, d + ld * 1024);
  };

  const int xsw = l15 & 7;
  const int cK0 = (lhi ^ xsw) << 4;
  const int cK1 = ((4 + lhi) ^ xsw) << 4;
  const int rowA = l15 * 128;
  const int rowB = ((wn & 1) * 64 + l15) * 128;

  bf16x8 af0[4][2], af1[4][2], bfr[2][2];
  auto readA = [&](int buf, int mh, bf16x8 (&af)[4][2]) {
    const char* base = smem + ((buf * 2 + wr) << 14) + mh * 8192 + rowA;
#pragma unroll
    for (int m = 0; m < 4; m++) {
      af[m][0] = *(const bf16x8*)(base + m * 2048 + cK0);
      af[m][1] = *(const bf16x8*)(base + m * 2048 + cK1);
    }
  };
  auto readB = [&](int buf, int nh) {
    const char* base = smem + 65536 + ((buf * 2 + (wn >> 1)) << 14) + nh * 4096 + rowB;
#pragma unroll
    for (int n = 0; n < 2; n++) {
      bfr[n][0] = *(const bf16x8*)(base + n * 2048 + cK0);
      bfr[n][1] = *(const bf16x8*)(base + n * 2048 + cK1);
    }
  };

  f32x4 acc[8][4];
#pragma unroll
  for (int m = 0; m < 8; m++)
#pragma unroll
    for (int n = 0; n < 4; n++) acc[m][n] = (f32x4){0, 0, 0, 0};

  auto mfmaQ = [&](int mh, int nh, bf16x8 (&af)[4][2]) {
    __builtin_amdgcn_s_setprio(1);
#pragma unroll
    for (int kk = 0; kk < 2; kk++)
#pragma unroll
      for (int m = 0; m < 4; m++)
#pragma unroll
        for (int n = 0; n < 2; n++)
          acc[mh * 4 + m][nh * 2 + n] = __builtin_amdgcn_mfma_f32_16x16x32_bf16(
              bfr[n][kk], af[m][kk], acc[mh * 4 + m][nh * 2 + n], 0, 0, 0);
    __builtin_amdgcn_s_setprio(0);
  };
  auto bar = [&] {
    asm volatile("" ::: "memory");
    __builtin_amdgcn_s_barrier();
    asm volatile("" ::: "memory");
  };

  const int NT = 32;
  // prologue: tile0 all halves + A halves of tile1; vmcnt(4) leaves A(1) in flight
  stageA(0, 0); stageA(0, 1); stageB(0, 0); stageB(0, 1);
  stageA(1, 0); stageA(1, 1);
  asm volatile("s_waitcnt vmcnt(4)" ::: "memory");
  bar();

  auto ktile = [&](int t, int buf) {
    const bool s1 = (t + 1 < NT);   // B halves of t+1 at P1/P2
    const bool s2 = (t + 2 < NT);   // A halves of t+2 at P3/P4
    // P1: reads A0+B0 (12), stage B0(t+1), MFMA q(0,0)
    readA(buf, 0, af0); readB(buf, 0);
    if (s1) stageB(t + 1, 0);
    bar(); mfmaQ(0, 0, af0); bar();
    // P2: reads A1 (8), stage B1(t+1), MFMA q(1,0)
    readA(buf, 1, af1);
    if (s1) stageB(t + 1, 1);
    bar(); mfmaQ(1, 0, af1); bar();
    // P3: reads B1 (4), stage A0(t+2), MFMA q(1,1)
    readB(buf, 1);
    if (s2) stageA(t + 2, 0);
    bar(); mfmaQ(1, 1, af1); bar();
    // P4: no reads, stage A1(t+2), MFMA q(0,1), counted vmcnt
    if (s2) stageA(t + 2, 1);
    bar(); mfmaQ(0, 1, af0);
    if (s2) asm volatile("s_waitcnt vmcnt(4)" ::: "memory");
    else    asm volatile("s_waitcnt vmcnt(0)" ::: "memory");
    bar();
  };

#pragma unroll 1
  for (int t = 0; t < NT; t += 2) {
    ktile(t, 0);
    ktile(t + 1, 1);
  }

  // swapped-operand C layout -> 8B packed stores
#pragma unroll
  for (int m = 0; m < 8; m++) {
    int grow = m0 + wr * 128 + m * 16 + l15;
#pragma unroll
    for (int n = 0; n < 4; n++) {
      int gcol = n0 + wn * 64 + n * 16 + lhi * 4;
      uint2 u;
      u.x = ((unsigned)f2b(acc[m][n][1]) << 16) | f2b(acc[m][n][0]);
      u.y = ((unsigned)f2b(acc[m][n][3]) << 16) | f2b(acc[m][n][2]);
      *(uint2*)(Hi + (size_t)grow * D_DIM + gcol) = u;
    }
  }
}

// ============ 256x256xBK=64 core, double-buffered, ONE __syncthreads per K-step ========
// (R6 structure, kept for gemm_score this round.)
template <int NT, int LDE>
__device__ __forceinline__ void core256(
    const bf16* __restrict__ Asrc, const bf16* __restrict__ Bsrc,
    char* smem, f32x4 (*acc)[4]) {
  const int tid = threadIdx.x;
  const int w = tid >> 6, L = tid & 63;
  const int l15 = L & 15, lhi = L >> 4;
  const int wr = w >> 2, wn = w & 3;

  const int srow = w * 16 + (L >> 3);
  const int sslot = ((L & 7) ^ ((L >> 3) & 7)) * 8;
  const bf16* pA[2][2];
  const bf16* pB[2][2];
#pragma unroll
  for (int h = 0; h < 2; h++)
#pragma unroll
    for (int ld = 0; ld < 2; ld++) {
      pA[h][ld] = Asrc + (size_t)(h * 128 + srow + ld * 8) * LDE + sslot;
      pB[h][ld] = Bsrc + (size_t)(h * 128 + srow + ld * 8) * LDE + sslot;
    }

  auto stage = [&](int t) {
    char* dA = smem + (t & 1) * 32768 + w * 2048;
    char* dB = smem + 65536 + (t & 1) * 32768 + w * 2048;
    const int ko = t * 64;
#pragma unroll
    for (int h = 0; h < 2; h++)
#pragma unroll
      for (int ld = 0; ld < 2; ld++) {
        load_lds16(pA[h][ld] + ko, dA + h * 16384 + ld * 1024);
        load_lds16(pB[h][ld] + ko, dB + h * 16384 + ld * 1024);
      }
  };

  const int xsw = l15 & 7;
  const int cK0 = (lhi ^ xsw) << 4;
  const int cK1 = ((4 + lhi) ^ xsw) << 4;

  stage(0);
#pragma unroll 2
  for (int t = 0; t < NT; ++t) {
    __syncthreads();
    if (t + 1 < NT) stage(t + 1);
    const char* bA = smem + (t & 1) * 32768;
    const char* bB = smem + 65536 + (t & 1) * 32768;
#pragma unroll
    for (int kk = 0; kk < 2; kk++) {
      const int cK = kk ? cK1 : cK0;
      bf16x8 af[8], bfv[4];
#pragma unroll
      for (int m = 0; m < 8; m++)
        af[m] = *(const bf16x8*)(bA + (wr * 128 + m * 16 + l15) * 128 + cK);
#pragma unroll
      for (int n = 0; n < 4; n++)
        bfv[n] = *(const bf16x8*)(bB + (wn * 64 + n * 16 + l15) * 128 + cK);
      __builtin_amdgcn_s_setprio(1);
#pragma unroll
      for (int m = 0; m < 8; m++)
#pragma unroll
        for (int n = 0; n < 4; n++)
          acc[m][n] = __builtin_amdgcn_mfma_f32_16x16x32_bf16(bfv[n], af[m], acc[m][n], 0, 0, 0);
      __builtin_amdgcn_s_setprio(0);
    }
  }
}

// ---------------- score GEMM: E = exp(SCALE * h1 h2^T), lower-tri 256 tiles ----------
__global__ __launch_bounds__(512, 2) void gemm_score(
    const bf16* __restrict__ H1, const bf16* __restrict__ H2,
    bf16* __restrict__ E, float* __restrict__ rowsum) {
  extern __shared__ char smem[];
  const int pid = blockIdx.x;
  const int b = pid & 7;
  const int tri = pid >> 3;
  int mt = (int)((sqrtf(8.0f * (float)tri + 1.0f) - 1.0f) * 0.5f);
  while ((mt + 1) * (mt + 2) / 2 <= tri) mt++;
  while (mt * (mt + 1) / 2 > tri) mt--;
  const int nt = tri - mt * (mt + 1) / 2;
  const int m0 = mt * 256, n0 = nt * 256;
  const bool diag = (mt == nt);
  const bf16* Ab = H1 + (size_t)b * S_DIM * D_DIM;
  const bf16* Bb = H2 + (size_t)b * S_DIM * D_DIM;
  bf16* Eb = E + (size_t)b * S_DIM * S_DIM;
  float* rs = rowsum + b * S_DIM;

  f32x4 acc[8][4];
#pragma unroll
  for (int m = 0; m < 8; m++)
#pragma unroll
    for (int n = 0; n < 4; n++) acc[m][n] = (f32x4){0, 0, 0, 0};

  core256<8, D_DIM>(Ab + (size_t)m0 * D_DIM, Bb + (size_t)n0 * D_DIM, smem, acc);

  const int tid = threadIdx.x;
  const int w = tid >> 6, L = tid & 63;
  const int l15 = L & 15, lhi = L >> 4;
  const int wr = w >> 2, wn = w & 3;
#pragma unroll
  for (int m = 0; m < 8; m++) {
    int sg = m0 + wr * 128 + m * 16 + l15;
    float rp = 0.0f;
#pragma unroll
    for (int n = 0; n < 4; n++) {
      int tg0 = n0 + wn * 64 + n * 16 + lhi * 4;
      unsigned short e[4];
#pragma unroll
      for (int r = 0; r < 4; r++) {
        float v = (!diag || (tg0 + r) <= sg) ? __expf(acc[m][n][r] * SCALE) : 0.0f;
        e[r] = f2b(v);
        rp += b2f(e[r]);
      }
      uint2 u;
      u.x = ((unsigned)e[1] << 16) | e[0];
      u.y = ((unsigned)e[3] << 16) | e[2];
      *(uint2*)(Eb + (size_t)sg * S_DIM + tg0) = u;
    }
    rp += __shfl_xor(rp, 16);
    rp += __shfl_xor(rp, 32);
    if (lhi == 0) atomicAdd(rs + sg, rp);
  }
}

// ---------------- PV GEMM: out[s][d] = (1/rowsum[s]) * sum_t E[s][t]*h1t[d][t] --------
__global__ __launch_bounds__(256, 2) void gemm_pv(
    const bf16* __restrict__ E, const bf16* __restrict__ H1T,
    const float* __restrict__ rowsum, float* __restrict__ out) {
  extern __shared__ char smem[];
  const int pid = blockIdx.x;
  const int b = pid & 7;
  const int r_ = pid >> 3;
  const int nt = r_ & 3;
  const int mb = r_ >> 2;
  const int mt = (mb < 8) ? 2 * mb : 31 - 2 * mb;
  const int m0 = mt * 128, n0 = nt * 128;
  const int NT = (mt + 1) * 2;
  const bf16* Ab = E + (size_t)b * S_DIM * S_DIM + (size_t)m0 * S_DIM;
  const bf16* Bb = H1T + (size_t)b * D_DIM * S_DIM + (size_t)n0 * S_DIM;
  const float* rs = rowsum + b * S_DIM;
  float* Cb = out + (size_t)b * S_DIM * D_DIM;

  const int tid = threadIdx.x;
  const int w = tid >> 6, L = tid & 63;
  const int l15 = L & 15, lhi = L >> 4;
  const int wr = w >> 1, wc = w & 1;

  const int srow = w * 8 + (L >> 3);
  const int sslot = ((L & 7) ^ ((L >> 3) & 7)) * 8;
  const bf16* pA[4];
  const bf16* pB[4];
#pragma unroll
  for (int ld = 0; ld < 4; ld++) {
    pA[ld] = Ab + (size_t)(ld * 32 + srow) * S_DIM + sslot;
    pB[ld] = Bb + (size_t)(ld * 32 + srow) * S_DIM + sslot;
  }

  auto stage = [&](int t) {
    char* dA = smem + (t & 1) * 16384 + w * 1024;
    char* dB = smem + 32768 + (t & 1) * 16384 + w * 1024;
    const int ko = t * 64;
#pragma unroll
    for (int ld = 0; ld < 4; ld++) {
      load_lds16(pA[ld] + ko, dA + ld * 4096);
      load_lds16(pB[ld] + ko, dB + ld * 4096);
    }
  };

  const int xsw = l15 & 7;
  const int cK0 = (lhi ^ xsw) << 4;
  const int cK1 = ((4 + lhi) ^ xsw) << 4;

  f32x4 acc[4][4];
#pragma unroll
  for (int m = 0; m < 4; m++)
#pragma unroll
    for (int n = 0; n < 4; n++) acc[m][n] = (f32x4){0, 0, 0, 0};

  stage(0);
  for (int t = 0; t < NT; ++t) {
    __syncthreads();
    if (t + 1 < NT) stage(t + 1);
    const char* bA = smem + (t & 1) * 16384;
    const char* bB = smem + 32768 + (t & 1) * 16384;
#pragma unroll
    for (int kk = 0; kk < 2; kk++) {
      const int cK = kk ? cK1 : cK0;
      bf16x8 af[4], bfv[4];
#pragma unroll
      for (int m = 0; m < 4; m++)
        af[m] = *(const bf16x8*)(bA + (wr * 64 + m * 16 + l15) * 128 + cK);
#pragma unroll
      for (int n = 0; n < 4; n++)
        bfv[n] = *(const bf16x8*)(bB + (wc * 64 + n * 16 + l15) * 128 + cK);
      __builtin_amdgcn_s_setprio(1);
#pragma unroll
      for (int m = 0; m < 4; m++)
#pragma unroll
        for (int n = 0; n < 4; n++)
          acc[m][n] = __builtin_amdgcn_mfma_f32_16x16x32_bf16(bfv[n], af[m], acc[m][n], 0, 0, 0);
      __builtin_amdgcn_s_setprio(0);
    }
  }

#pragma unroll
  for (int m = 0; m < 4; m++) {
    int sg = m0 + wr * 64 + m * 16 + l15;
    float inv = 1.0f / rs[sg];
#pragma unroll
    for (int n = 0; n < 4; n++) {
      int gcol = n0 + wc * 64 + n * 16 + lhi * 4;
      float4 o;
      o.x = acc[m][n][0] * inv;
      o.y = acc[m][n][1] * inv;
      o.z = acc[m][n][2] * inv;
      o.w = acc[m][n][3] * inv;
      *(float4*)(Cb + (size_t)sg * D_DIM + gcol) = o;
    }
  }
}

extern "C" void kernel_launch(void* const* d_in, const int* in_sizes, int n_in,
                              void* d_out, int out_size, void* d_ws, size_t ws_size,
                              hipStream_t stream) {
  const float* x1 = (const float*)d_in[0];
  const float* x2 = (const float*)d_in[1];
  const float* km = (const float*)d_in[2];
  float* out = (float*)d_out;
  char* ws = (char*)d_ws;
  bf16* E    = (bf16*)(ws);
  bf16* Kbf  = (bf16*)(ws);
  bf16* x1t  = (bf16*)(ws + (8ull << 20));
  bf16* x2t  = (bf16*)(ws + (24ull << 20));
  bf16* h1n  = (bf16*)(ws + (64ull << 20));
  bf16* h2n  = (bf16*)(ws + (80ull << 20));
  bf16* h1t  = (bf16*)(ws + (96ull << 20));
  float* rowsum = (float*)(ws + (112ull << 20));

  convert_k<<<2048, 256, 0, stream>>>(km, Kbf, (S_DIM * S_DIM) / 8);
  transpose_f2b<<<dim3(16, 64, 8), 256, 0, stream>>>(x1, x1t);
  transpose_f2b<<<dim3(16, 64, 8), 256, 0, stream>>>(x2, x2t);
  gemm_h<<<256, 512, 131072, stream>>>(Kbf, x1t, h1n);
  transpose_b2b<<<dim3(16, 64, 8), 256, 0, stream>>>(h1n, h1t);
  hipMemsetAsync(rowsum, 0, B_DIM * S_DIM * sizeof(float), stream);
  gemm_score<<<288, 512, 131072, stream>>>(h1n, h2n, E, rowsum);
  gemm_pv<<<512, 256, 65536, stream>>>(E, h1t, rowsum, out);
}

// Round 8
// 173.850 us; speedup vs baseline: 1.3732x; 1.3732x over previous
//
#include <hip/hip_runtime.h>
#include <hip/hip_bf16.h>

#define S_DIM 2048
#define D_DIM 512
#define B_DIM 8
#define SCALE 0.02209708691207961f  // 1/sqrt(2048)

typedef __hip_bfloat16 bf16;
typedef short bf16x8 __attribute__((ext_vector_type(8)));
typedef float f32x4 __attribute__((ext_vector_type(4)));

__device__ __forceinline__ unsigned short f2b(float f) {
  __hip_bfloat16 h = __float2bfloat16(f);
  return __builtin_bit_cast(unsigned short, h);
}
__device__ __forceinline__ float b2f(unsigned short s) {
  return __bfloat162float(__builtin_bit_cast(__hip_bfloat16, s));
}

__device__ __forceinline__ void load_lds16(const void* g, void* l) {
  __builtin_amdgcn_global_load_lds((const __attribute__((address_space(1))) void*)g,
                                   (__attribute__((address_space(3))) void*)l, 16, 0, 0);
}

// ---------------- kernel matrix f32 -> bf16 ----------------
__global__ void convert_k(const float* __restrict__ in, bf16* __restrict__ out, int n8) {
  int i = blockIdx.x * blockDim.x + threadIdx.x;
  if (i >= n8) return;
  const float4* p = (const float4*)in;
  float4 a = p[2 * i], b = p[2 * i + 1];
  bf16x8 r;
  r[0] = f2b(a.x); r[1] = f2b(a.y); r[2] = f2b(a.z); r[3] = f2b(a.w);
  r[4] = f2b(b.x); r[5] = f2b(b.y); r[6] = f2b(b.z); r[7] = f2b(b.w);
  ((bf16x8*)out)[i] = r;
}

// ---------------- transpose x1,x2 (S,D) f32 -> (D,S) bf16, 64x64 tiles ----------------
// One dispatch for both inputs (z<8: x1, else x2). Loads 256B/row; stores uint2 (128B/row).
__global__ void tr_f2b64(const float* __restrict__ x1, const float* __restrict__ x2,
                         bf16* __restrict__ out) {
  __shared__ unsigned short t[64][66];   // [d][s], pad 66 (odd dword stride)
  const int z = blockIdx.z;
  const float* in = (z < 8 ? x1 : x2) + (size_t)(z & 7) * (S_DIM * D_DIM);
  bf16* ob = out + (size_t)z * (size_t)(D_DIM * S_DIM);
  const int r0 = blockIdx.y * 64;   // S
  const int c0 = blockIdx.x * 64;   // D
  const int tid = threadIdx.x;
  const int lr = tid >> 6, lc = tid & 63;
#pragma unroll
  for (int i = 0; i < 16; i++) {
    int r = i * 4 + lr;
    t[lc][r] = f2b(in[(size_t)(r0 + r) * D_DIM + c0 + lc]);
  }
  __syncthreads();
  const int dl = tid >> 4, tq = tid & 15;
#pragma unroll
  for (int j = 0; j < 4; j++) {
    int d = j * 16 + dl;
    const unsigned short* p = &t[d][tq * 4];
    uint2 u;
    u.x = (unsigned)p[0] | ((unsigned)p[1] << 16);
    u.y = (unsigned)p[2] | ((unsigned)p[3] << 16);
    *(uint2*)(ob + (size_t)(c0 + d) * S_DIM + r0 + tq * 4) = u;
  }
}

// ---------------- transpose h1n (S,D) bf16 -> (D,S) bf16, 64x64 tiles ----------------
__global__ void tr_b2b64(const bf16* __restrict__ in, bf16* __restrict__ out) {
  __shared__ unsigned short t[64][66];
  const int z = blockIdx.z;   // batch
  const bf16* ib = in + (size_t)z * (S_DIM * D_DIM);
  bf16* ob = out + (size_t)z * (S_DIM * D_DIM);
  const int r0 = blockIdx.y * 64;   // S
  const int c0 = blockIdx.x * 64;   // D
  const int tid = threadIdx.x;
  const int lr = tid >> 5, cp = tid & 31;
#pragma unroll
  for (int i = 0; i < 8; i++) {
    int r = i * 8 + lr;
    unsigned v = *(const unsigned*)(ib + (size_t)(r0 + r) * D_DIM + c0 + cp * 2);
    t[cp * 2][r] = (unsigned short)(v & 0xffff);
    t[cp * 2 + 1][r] = (unsigned short)(v >> 16);
  }
  __syncthreads();
  const int dl = tid >> 4, tq = tid & 15;
#pragma unroll
  for (int j = 0; j < 4; j++) {
    int d = j * 16 + dl;
    const unsigned short* p = &t[d][tq * 4];
    uint2 u;
    u.x = (unsigned)p[0] | ((unsigned)p[1] << 16);
    u.y = (unsigned)p[2] | ((unsigned)p[3] << 16);
    *(uint2*)(ob + (size_t)(c0 + d) * S_DIM + r0 + tq * 4) = u;
  }
}

// ---------------- h-GEMM (R4-verbatim, 73.4us proven): 256x256xBK=32, triple-buffer ----
// 8 waves (2m x 4n), per-wave 128x64. LDS 96KB (A 3x16KB @0, B 3x16KB @48KB), vmcnt(4),
// 1 barrier/step. Swizzle (0 conflicts measured): LDS[row][slot16B]=G[row][slot^((row>>1)&3)].
// MFMA operand-swapped: lane holds 4 consecutive output cols -> 8B packed stores.
__global__ __launch_bounds__(512, 2) void gemm_h(
    const bf16* __restrict__ A, const bf16* __restrict__ X, bf16* __restrict__ H) {
  extern __shared__ char smem[];
  const int pid = blockIdx.x;
  const int mt = pid & 7;              // XCD-pinned A panel
  const int r_ = pid >> 3;
  const int ntile = r_ & 1;
  const int item = r_ >> 1;            // 0..15
  const int m0 = mt * 256, n0 = ntile * 256;
  const bf16* Xi = X + (size_t)item * (D_DIM * S_DIM);
  bf16* Hi = H + (size_t)item * (S_DIM * D_DIM);

  const int tid = threadIdx.x;
  const int w = tid >> 6, L = tid & 63;
  const int l15 = L & 15, lhi = L >> 4;
  const int wr = w >> 2, wn = w & 3;

  const int srow = tid >> 2;
  const int sslot = ((tid & 3) ^ ((tid >> 3) & 3)) * 8;
  const bf16* pA[2];
  const bf16* pB[2];
#pragma unroll
  for (int ld = 0; ld < 2; ld++) {
    pA[ld] = A + (size_t)(m0 + ld * 128 + srow) * 2048 + sslot;
    pB[ld] = Xi + (size_t)(n0 + ld * 128 + srow) * 2048 + sslot;
  }

  char* A0 = smem;          char* A1 = smem + 16384;  char* A2 = smem + 32768;
  char* B0 = smem + 49152;  char* B1 = smem + 65536;  char* B2 = smem + 81920;

  auto stage = [&](int t2, char* dA, char* dB) {
#pragma unroll
    for (int ld = 0; ld < 2; ld++)
      load_lds16(pA[ld] + t2 * 32, dA + ld * 8192 + w * 1024);
#pragma unroll
    for (int ld = 0; ld < 2; ld++)
      load_lds16(pB[ld] + t2 * 32, dB + ld * 8192 + w * 1024);
  };

  const int xo = (lhi ^ ((l15 >> 1) & 3)) << 4;
  int offA[8], offB[4];
#pragma unroll
  for (int m = 0; m < 8; m++) offA[m] = (wr * 128 + m * 16 + l15) * 64 + xo;
#pragma unroll
  for (int n = 0; n < 4; n++) offB[n] = (wn * 64 + n * 16 + l15) * 64 + xo;

  f32x4 acc[8][4];
#pragma unroll
  for (int m = 0; m < 8; m++)
#pragma unroll
    for (int n = 0; n < 4; n++) acc[m][n] = (f32x4){0, 0, 0, 0};

  stage(0, A0, B0);
  stage(1, A1, B1);

#pragma unroll 1
  for (int t = 0; t < 64; ++t) {
    if (t < 63) asm volatile("s_waitcnt vmcnt(4)" ::: "memory");
    else        asm volatile("s_waitcnt vmcnt(0)" ::: "memory");
    __builtin_amdgcn_s_barrier();
    asm volatile("" ::: "memory");
    if (t < 62) stage(t + 2, A2, B2);

    bf16x8 af[8], bfv[4];
#pragma unroll
    for (int m = 0; m < 8; m++) af[m] = *(const bf16x8*)(A0 + offA[m]);
#pragma unroll
    for (int n = 0; n < 4; n++) bfv[n] = *(const bf16x8*)(B0 + offB[n]);
    __builtin_amdgcn_s_setprio(1);
#pragma unroll
    for (int m = 0; m < 8; m++)
#pragma unroll
      for (int n = 0; n < 4; n++)
        acc[m][n] = __builtin_amdgcn_mfma_f32_16x16x32_bf16(bfv[n], af[m], acc[m][n], 0, 0, 0);
    __builtin_amdgcn_s_setprio(0);

    char* tA = A0; A0 = A1; A1 = A2; A2 = tA;
    char* tB = B0; B0 = B1; B1 = B2; B2 = tB;
  }

#pragma unroll
  for (int m = 0; m < 8; m++) {
    int grow = m0 + wr * 128 + m * 16 + l15;
#pragma unroll
    for (int n = 0; n < 4; n++) {
      int gcol = n0 + wn * 64 + n * 16 + lhi * 4;
      uint2 u;
      u.x = ((unsigned)f2b(acc[m][n][1]) << 16) | f2b(acc[m][n][0]);
      u.y = ((unsigned)f2b(acc[m][n][3]) << 16) | f2b(acc[m][n][2]);
      *(uint2*)(Hi + (size_t)grow * D_DIM + gcol) = u;
    }
  }
}

// ---------------- score GEMM (R4-verbatim): E = exp(SCALE*h1 h2^T), lower-tri 256 ----
__global__ __launch_bounds__(512, 2) void gemm_score(
    const bf16* __restrict__ H1, const bf16* __restrict__ H2,
    bf16* __restrict__ E, float* __restrict__ rowsum) {
  extern __shared__ char smem[];
  const int pid = blockIdx.x;
  const int b = pid & 7;
  const int tri = pid >> 3;
  int mt = (int)((sqrtf(8.0f * (float)tri + 1.0f) - 1.0f) * 0.5f);
  while ((mt + 1) * (mt + 2) / 2 <= tri) mt++;
  while (mt * (mt + 1) / 2 > tri) mt--;
  const int nt = tri - mt * (mt + 1) / 2;
  const int m0 = mt * 256, n0 = nt * 256;
  const bool diag = (mt == nt);
  const bf16* Ab = H1 + (size_t)b * S_DIM * D_DIM;
  const bf16* Bb = H2 + (size_t)b * S_DIM * D_DIM;
  bf16* Eb = E + (size_t)b * S_DIM * S_DIM;
  float* rs = rowsum + b * S_DIM;

  const int tid = threadIdx.x;
  const int w = tid >> 6, L = tid & 63;
  const int l15 = L & 15, lhi = L >> 4;
  const int wr = w >> 2, wn = w & 3;

  const int srow = tid >> 2;
  const int sslot = ((tid & 3) ^ ((tid >> 3) & 3)) * 8;
  const bf16* pA[2];
  const bf16* pB[2];
#pragma unroll
  for (int ld = 0; ld < 2; ld++) {
    pA[ld] = Ab + (size_t)(m0 + ld * 128 + srow) * D_DIM + sslot;
    pB[ld] = Bb + (size_t)(n0 + ld * 128 + srow) * D_DIM + sslot;
  }

  char* A0 = smem;          char* A1 = smem + 16384;  char* A2 = smem + 32768;
  char* B0 = smem + 49152;  char* B1 = smem + 65536;  char* B2 = smem + 81920;

  auto stage = [&](int t2, char* dA, char* dB) {
#pragma unroll
    for (int ld = 0; ld < 2; ld++)
      load_lds16(pA[ld] + t2 * 32, dA + ld * 8192 + w * 1024);
#pragma unroll
    for (int ld = 0; ld < 2; ld++)
      load_lds16(pB[ld] + t2 * 32, dB + ld * 8192 + w * 1024);
  };

  const int xo = (lhi ^ ((l15 >> 1) & 3)) << 4;
  int offA[8], offB[4];
#pragma unroll
  for (int m = 0; m < 8; m++) offA[m] = (wr * 128 + m * 16 + l15) * 64 + xo;
#pragma unroll
  for (int n = 0; n < 4; n++) offB[n] = (wn * 64 + n * 16 + l15) * 64 + xo;

  f32x4 acc[8][4];
#pragma unroll
  for (int m = 0; m < 8; m++)
#pragma unroll
    for (int n = 0; n < 4; n++) acc[m][n] = (f32x4){0, 0, 0, 0};

  stage(0, A0, B0);
  stage(1, A1, B1);

#pragma unroll 1
  for (int t = 0; t < 16; ++t) {
    if (t < 15) asm volatile("s_waitcnt vmcnt(4)" ::: "memory");
    else        asm volatile("s_waitcnt vmcnt(0)" ::: "memory");
    __builtin_amdgcn_s_barrier();
    asm volatile("" ::: "memory");
    if (t < 14) stage(t + 2, A2, B2);

    bf16x8 af[8], bfv[4];
#pragma unroll
    for (int m = 0; m < 8; m++) af[m] = *(const bf16x8*)(A0 + offA[m]);
#pragma unroll
    for (int n = 0; n < 4; n++) bfv[n] = *(const bf16x8*)(B0 + offB[n]);
    __builtin_amdgcn_s_setprio(1);
#pragma unroll
    for (int m = 0; m < 8; m++)
#pragma unroll
      for (int n = 0; n < 4; n++)
        acc[m][n] = __builtin_amdgcn_mfma_f32_16x16x32_bf16(bfv[n], af[m], acc[m][n], 0, 0, 0);
    __builtin_amdgcn_s_setprio(0);

    char* tA = A0; A0 = A1; A1 = A2; A2 = tA;
    char* tB = B0; B0 = B1; B1 = B2; B2 = tB;
  }

#pragma unroll
  for (int m = 0; m < 8; m++) {
    int sg = m0 + wr * 128 + m * 16 + l15;
    float rp = 0.0f;
#pragma unroll
    for (int n = 0; n < 4; n++) {
      int tg0 = n0 + wn * 64 + n * 16 + lhi * 4;
      unsigned short e[4];
#pragma unroll
      for (int r = 0; r < 4; r++) {
        float v = (!diag || (tg0 + r) <= sg) ? __expf(acc[m][n][r] * SCALE) : 0.0f;
        e[r] = f2b(v);
        rp += b2f(e[r]);
      }
      uint2 u;
      u.x = ((unsigned)e[1] << 16) | e[0];
      u.y = ((unsigned)e[3] << 16) | e[2];
      *(uint2*)(Eb + (size_t)sg * S_DIM + tg0) = u;
    }
    rp += __shfl_xor(rp, 16);
    rp += __shfl_xor(rp, 32);
    if (lhi == 0) atomicAdd(rs + sg, rp);
  }
}

// ---------------- PV GEMM: R4 triple-buffer core at 128x128xBK=32 -------------------
// out[s][d] = (1/rowsum[s]) * sum_t E[s][t]*h1t[d][t]. 4 waves (2m x 2n), per-wave 64x64.
// LDS 48KB (A 3x8KB @0, B 3x8KB @24KB) -> 3 blocks/CU; vmcnt(4); R4's exact swizzle.
// Causal K-trim NT=(mt+1)*2 (BK=32 -> *4); mt-pairing balances K-depth.
__global__ __launch_bounds__(256, 2) void gemm_pv(
    const bf16* __restrict__ E, const bf16* __restrict__ H1T,
    const float* __restrict__ rowsum, float* __restrict__ out) {
  extern __shared__ char smem[];
  const int pid = blockIdx.x;
  const int b = pid & 7;
  const int r_ = pid >> 3;
  const int nt = r_ & 3;
  const int mb = r_ >> 2;
  const int mt = (mb < 8) ? 2 * mb : 31 - 2 * mb;
  const int m0 = mt * 128, n0 = nt * 128;
  const int NT = (mt + 1) * 4;     // K-tiles of 32
  const bf16* Ab = E + (size_t)b * S_DIM * S_DIM + (size_t)m0 * S_DIM;
  const bf16* Bb = H1T + (size_t)b * D_DIM * S_DIM + (size_t)n0 * S_DIM;
  const float* rs = rowsum + b * S_DIM;
  float* Cb = out + (size_t)b * S_DIM * D_DIM;

  const int tid = threadIdx.x;
  const int w = tid >> 6, L = tid & 63;
  const int l15 = L & 15, lhi = L >> 4;
  const int wr = w >> 1, wc = w & 1;

  const int srow = tid >> 2;                       // 0..63
  const int sslot = ((tid & 3) ^ ((tid >> 3) & 3)) * 8;
  const bf16* pA[2];
  const bf16* pB[2];
#pragma unroll
  for (int ld = 0; ld < 2; ld++) {
    pA[ld] = Ab + (size_t)(ld * 64 + srow) * S_DIM + sslot;
    pB[ld] = Bb + (size_t)(ld * 64 + srow) * S_DIM + sslot;
  }

  char* A0 = smem;          char* A1 = smem + 8192;   char* A2 = smem + 16384;
  char* B0 = smem + 24576;  char* B1 = smem + 32768;  char* B2 = smem + 40960;

  auto stage = [&](int t2, char* dA, char* dB) {
#pragma unroll
    for (int ld = 0; ld < 2; ld++)
      load_lds16(pA[ld] + t2 * 32, dA + ld * 4096 + w * 1024);
#pragma unroll
    for (int ld = 0; ld < 2; ld++)
      load_lds16(pB[ld] + t2 * 32, dB + ld * 4096 + w * 1024);
  };

  const int xo = (lhi ^ ((l15 >> 1) & 3)) << 4;
  int offA[4], offB[4];
#pragma unroll
  for (int m = 0; m < 4; m++) offA[m] = (wr * 64 + m * 16 + l15) * 64 + xo;
#pragma unroll
  for (int n = 0; n < 4; n++) offB[n] = (wc * 64 + n * 16 + l15) * 64 + xo;

  f32x4 acc[4][4];
#pragma unroll
  for (int m = 0; m < 4; m++)
#pragma unroll
    for (int n = 0; n < 4; n++) acc[m][n] = (f32x4){0, 0, 0, 0};

  stage(0, A0, B0);
  stage(1, A1, B1);

#pragma unroll 1
  for (int t = 0; t < NT; ++t) {
    if (t < NT - 1) asm volatile("s_waitcnt vmcnt(4)" ::: "memory");
    else            asm volatile("s_waitcnt vmcnt(0)" ::: "memory");
    __builtin_amdgcn_s_barrier();
    asm volatile("" ::: "memory");
    if (t + 2 < NT) stage(t + 2, A2, B2);

    bf16x8 af[4], bfv[4];
#pragma unroll
    for (int m = 0; m < 4; m++) af[m] = *(const bf16x8*)(A0 + offA[m]);
#pragma unroll
    for (int n = 0; n < 4; n++) bfv[n] = *(const bf16x8*)(B0 + offB[n]);
    __builtin_amdgcn_s_setprio(1);
#pragma unroll
    for (int m = 0; m < 4; m++)
#pragma unroll
      for (int n = 0; n < 4; n++)
        acc[m][n] = __builtin_amdgcn_mfma_f32_16x16x32_bf16(bfv[n], af[m], acc[m][n], 0, 0, 0);
    __builtin_amdgcn_s_setprio(0);

    char* tA = A0; A0 = A1; A1 = A2; A2 = tA;
    char* tB = B0; B0 = B1; B1 = B2; B2 = tB;
  }

  // swapped layout: lane -> row m*16+l15, cols n*16+lhi*4+{0..3} -> float4 stores
#pragma unroll
  for (int m = 0; m < 4; m++) {
    int sg = m0 + wr * 64 + m * 16 + l15;
    float inv = 1.0f / rs[sg];
#pragma unroll
    for (int n = 0; n < 4; n++) {
      int gcol = n0 + wc * 64 + n * 16 + lhi * 4;
      float4 o;
      o.x = acc[m][n][0] * inv;
      o.y = acc[m][n][1] * inv;
      o.z = acc[m][n][2] * inv;
      o.w = acc[m][n][3] * inv;
      *(float4*)(Cb + (size_t)sg * D_DIM + gcol) = o;
    }
  }
}

extern "C" void kernel_launch(void* const* d_in, const int* in_sizes, int n_in,
                              void* d_out, int out_size, void* d_ws, size_t ws_size,
                              hipStream_t stream) {
  const float* x1 = (const float*)d_in[0];
  const float* x2 = (const float*)d_in[1];
  const float* km = (const float*)d_in[2];
  float* out = (float*)d_out;
  char* ws = (char*)d_ws;
  // ws layout (bytes):
  //   [0,64M):   E (8 x 2048 x 2048 bf16) -- overlaps phase-1 temporaries below
  //   [0,8M):    Kbf | [8,24M): x1t | [24,40M): x2t   (dead before E is written)
  //   [64,80M):  h1n  [80,96M): h2n  [96,112M): h1t
  //   [112M,+64K): rowsum (8 x 2048 f32)
  bf16* E    = (bf16*)(ws);
  bf16* Kbf  = (bf16*)(ws);
  bf16* x1t  = (bf16*)(ws + (8ull << 20));
  bf16* h1n  = (bf16*)(ws + (64ull << 20));
  bf16* h2n  = (bf16*)(ws + (80ull << 20));
  bf16* h1t  = (bf16*)(ws + (96ull << 20));
  float* rowsum = (float*)(ws + (112ull << 20));

  convert_k<<<2048, 256, 0, stream>>>(km, Kbf, (S_DIM * S_DIM) / 8);
  // x1t..x2t contiguous: 16 items of (512,2048)
  tr_f2b64<<<dim3(8, 32, 16), 256, 0, stream>>>(x1, x2, x1t);
  gemm_h<<<256, 512, 98304, stream>>>(Kbf, x1t, h1n);
  tr_b2b64<<<dim3(8, 32, 8), 256, 0, stream>>>(h1n, h1t);
  hipMemsetAsync(rowsum, 0, B_DIM * S_DIM * sizeof(float), stream);
  gemm_score<<<288, 512, 98304, stream>>>(h1n, h2n, E, rowsum);
  gemm_pv<<<512, 256, 49152, stream>>>(E, h1t, rowsum, out);
}